// Round 11
// baseline (45.712 us; speedup 1.0000x reference)
//
#include <hip/hip_runtime.h>

// Problem constants (match reference)
#define PNX 432
#define PNY 496
#define PNC 64
#define PLANE (PNY * PNX)   // 214272 = 837*256

typedef float f32x4 __attribute__((ext_vector_type(4)));

// ---------------- scatter + zrow init ----------------
// Scatter pillar index p into map at its global cell (cells unique).
// Also zeroes the 64-float zrow (read by gather for empty cells).
// map is NEVER cleared — gather self-validates entries against coords,
// so poison/stale values are rejected (or already correct).
__global__ void pp_scatter_map(const int4* __restrict__ coords,
                               int* __restrict__ map,
                               float* __restrict__ zrow, int P) {
    int p = blockIdx.x * blockDim.x + threadIdx.x;
    if (blockIdx.x == 0 && threadIdx.x < PNC) zrow[threadIdx.x] = 0.0f;
    if (p >= P) return;
    int4 c = coords[p];              // (b, z, y, x)
    int gidx = c.x * PLANE + c.y + c.z * PNX + c.w;
    map[gidx] = p;
}

// ---------------- gather (self-validating map) ----------------
// One thread per cell; 1024-thread blocks so each block writes 4KB
// contiguous per channel-plane (DRAM page locality on the write walk).
__global__ void __launch_bounds__(1024)
pp_gather(const float* __restrict__ feat,
          const int* __restrict__ map,
          const int4* __restrict__ coords,
          const float* __restrict__ zrow,
          float* __restrict__ out, int ncells, int P) {
    int cell = blockIdx.x * blockDim.x + threadIdx.x;
    if (cell >= ncells) return;
    int b = cell / PLANE;
    int spat = cell - b * PLANE;

    int pm = map[cell];
    unsigned upm = (unsigned)pm;
    int pms = (upm < (unsigned)P) ? pm : 0;          // safe index
    int4 c = coords[pms];                            // L2-resident (1MB)
    bool valid = (upm < (unsigned)P) &&
                 (c.x * PLANE + c.y + c.z * PNX + c.w == cell);

    const float* src = valid ? (feat + (size_t)pms * PNC) : zrow;
    const f32x4* fp = reinterpret_cast<const f32x4*>(src);

    f32x4 r[16];
    #pragma unroll
    for (int g = 0; g < 16; ++g) r[g] = fp[g];

    float* o = out + (size_t)b * PNC * PLANE + spat;
    #pragma unroll
    for (int g = 0; g < 16; ++g) {
        o[(size_t)(4 * g + 0) * PLANE] = r[g].x;
        o[(size_t)(4 * g + 1) * PLANE] = r[g].y;
        o[(size_t)(4 * g + 2) * PLANE] = r[g].z;
        o[(size_t)(4 * g + 3) * PLANE] = r[g].w;
    }
}

// ---------------- fallback path (ws too small) ----------------

__global__ void pp_zero_out(f32x4* __restrict__ out4, size_t n4) {
    size_t t = (size_t)blockIdx.x * blockDim.x + threadIdx.x;
    size_t stride = (size_t)gridDim.x * blockDim.x;
    const f32x4 z = {0.f, 0.f, 0.f, 0.f};
    for (size_t i = t; i < n4; i += stride) out4[i] = z;
}

__global__ void pp_scatter_direct(const float* __restrict__ feat,
                                  const int4* __restrict__ coords,
                                  float* __restrict__ out, int P) {
    int t = blockIdx.x * blockDim.x + threadIdx.x;
    int p = t >> 6;
    int c = t & 63;
    if (p >= P) return;
    int4 co = coords[p];
    size_t oidx = ((size_t)(co.x * PNC + c)) * PLANE + co.y + co.z * PNX + co.w;
    out[oidx] = feat[p * PNC + c];
}

extern "C" void kernel_launch(void* const* d_in, const int* in_sizes, int n_in,
                              void* d_out, int out_size, void* d_ws, size_t ws_size,
                              hipStream_t stream) {
    const float* feat = (const float*)d_in[0];
    const int4* coords = (const int4*)d_in[1];
    float* out = (float*)d_out;

    const int P = in_sizes[0] / PNC;                 // 64000
    const int B = out_size / (PNC * PLANE);          // 4
    const int ncells = B * PLANE;                    // 857088
    const size_t mapBytes = (size_t)ncells * sizeof(int);   // 16B-aligned
    const size_t needBytes = mapBytes + PNC * sizeof(float);

    if (ws_size >= needBytes) {
        int* map = (int*)d_ws;
        float* zrow = (float*)((char*)d_ws + mapBytes);
        pp_scatter_map<<<(P + 255) / 256, 256, 0, stream>>>(coords, map, zrow, P);
        pp_gather<<<(ncells + 1023) / 1024, 1024, 0, stream>>>(feat, map, coords,
                                                               zrow, out, ncells, P);
    } else {
        // Fallback: zero-fill + direct scatter (correct but more HBM traffic)
        size_t n4 = (size_t)out_size / 4;
        pp_zero_out<<<2048, 256, 0, stream>>>((f32x4*)out, n4);
        int total = P * PNC;
        pp_scatter_direct<<<(total + 255) / 256, 256, 0, stream>>>(feat, coords, out, P);
    }
}

// Round 12
// 44.559 us; speedup vs baseline: 1.0259x; 1.0259x over previous
//
#include <hip/hip_runtime.h>

// Problem constants (match reference)
#define PNX 432
#define PNY 496
#define PNC 64
#define PLANE (PNY * PNX)   // 214272 = 837*256

typedef float f32x4 __attribute__((ext_vector_type(4)));

// ---------------- scatter + zrow init ----------------
// Scatter pillar index p into map at its global cell (cells unique).
// Also zeroes the 64-float zrow (read by gather for empty cells).
// map is NEVER cleared — gather self-validates entries against coords,
// so poison/stale values are rejected (or, for stale entries from a
// previous identical call, already correct).
__global__ void pp_scatter_map(const int4* __restrict__ coords,
                               int* __restrict__ map,
                               float* __restrict__ zrow, int P) {
    int p = blockIdx.x * blockDim.x + threadIdx.x;
    if (blockIdx.x == 0 && threadIdx.x < PNC) zrow[threadIdx.x] = 0.0f;
    if (p >= P) return;
    int4 c = coords[p];              // (b, z, y, x)
    int gidx = c.x * PLANE + c.y + c.z * PNX + c.w;
    map[gidx] = p;
}

// ---------------- gather (self-validating map) ----------------
// One thread per cell: map read, coords-validate, branch-free zrow
// select, 16 contiguous f32x4 row loads, 64 dword stores
// (256B contiguous per wave-store instruction).
// Measured best structure (R5/R9): multi-row-gather variants, wide-store
// variants, LDS-transpose, and 1024-thread blocks all benched slower.
__global__ void pp_gather(const float* __restrict__ feat,
                          const int* __restrict__ map,
                          const int4* __restrict__ coords,
                          const float* __restrict__ zrow,
                          float* __restrict__ out, int ncells, int P) {
    int cell = blockIdx.x * blockDim.x + threadIdx.x;
    if (cell >= ncells) return;
    int b = cell / PLANE;
    int spat = cell - b * PLANE;

    int pm = map[cell];
    unsigned upm = (unsigned)pm;
    int pms = (upm < (unsigned)P) ? pm : 0;          // safe index
    int4 c = coords[pms];                            // L2-resident (1MB)
    bool valid = (upm < (unsigned)P) &&
                 (c.x * PLANE + c.y + c.z * PNX + c.w == cell);

    const float* src = valid ? (feat + (size_t)pms * PNC) : zrow;
    const f32x4* fp = reinterpret_cast<const f32x4*>(src);

    f32x4 r[16];
    #pragma unroll
    for (int g = 0; g < 16; ++g) r[g] = fp[g];

    float* o = out + (size_t)b * PNC * PLANE + spat;
    #pragma unroll
    for (int g = 0; g < 16; ++g) {
        o[(size_t)(4 * g + 0) * PLANE] = r[g].x;
        o[(size_t)(4 * g + 1) * PLANE] = r[g].y;
        o[(size_t)(4 * g + 2) * PLANE] = r[g].z;
        o[(size_t)(4 * g + 3) * PLANE] = r[g].w;
    }
}

// ---------------- fallback path (ws too small) ----------------

__global__ void pp_zero_out(f32x4* __restrict__ out4, size_t n4) {
    size_t t = (size_t)blockIdx.x * blockDim.x + threadIdx.x;
    size_t stride = (size_t)gridDim.x * blockDim.x;
    const f32x4 z = {0.f, 0.f, 0.f, 0.f};
    for (size_t i = t; i < n4; i += stride) out4[i] = z;
}

__global__ void pp_scatter_direct(const float* __restrict__ feat,
                                  const int4* __restrict__ coords,
                                  float* __restrict__ out, int P) {
    int t = blockIdx.x * blockDim.x + threadIdx.x;
    int p = t >> 6;
    int c = t & 63;
    if (p >= P) return;
    int4 co = coords[p];
    size_t oidx = ((size_t)(co.x * PNC + c)) * PLANE + co.y + co.z * PNX + co.w;
    out[oidx] = feat[p * PNC + c];
}

extern "C" void kernel_launch(void* const* d_in, const int* in_sizes, int n_in,
                              void* d_out, int out_size, void* d_ws, size_t ws_size,
                              hipStream_t stream) {
    const float* feat = (const float*)d_in[0];
    const int4* coords = (const int4*)d_in[1];
    float* out = (float*)d_out;

    const int P = in_sizes[0] / PNC;                 // 64000
    const int B = out_size / (PNC * PLANE);          // 4
    const int ncells = B * PLANE;                    // 857088
    const size_t mapBytes = (size_t)ncells * sizeof(int);   // 16B-aligned
    const size_t needBytes = mapBytes + PNC * sizeof(float);

    if (ws_size >= needBytes) {
        int* map = (int*)d_ws;
        float* zrow = (float*)((char*)d_ws + mapBytes);
        pp_scatter_map<<<(P + 255) / 256, 256, 0, stream>>>(coords, map, zrow, P);
        pp_gather<<<(ncells + 255) / 256, 256, 0, stream>>>(feat, map, coords,
                                                            zrow, out, ncells, P);
    } else {
        // Fallback: zero-fill + direct scatter (correct but more HBM traffic)
        size_t n4 = (size_t)out_size / 4;
        pp_zero_out<<<2048, 256, 0, stream>>>((f32x4*)out, n4);
        int total = P * PNC;
        pp_scatter_direct<<<(total + 255) / 256, 256, 0, stream>>>(feat, coords, out, P);
    }
}